// Round 1
// baseline (1948.999 us; speedup 1.0000x reference)
//
#include <hip/hip_runtime.h>
#include <hip/hip_bf16.h>
#include <math.h>

#define HH 512
#define WW 512
#define BB 4
#define SS 40
#define NPT 512
#define PADC 32
#define OUTW 448

__device__ inline float2 cmulf(float2 a, float2 b) {
    return make_float2(a.x*b.x - a.y*b.y, a.x*b.y + a.y*b.x);
}
__device__ inline float bf2f(unsigned short u) {
    unsigned int x = ((unsigned int)u) << 16;
    return __uint_as_float(x);
}
__device__ inline unsigned short f2bf(float f) {
    unsigned int x = __float_as_uint(f);
    unsigned int lsb = (x >> 16) & 1u;
    x += 0x7fffu + lsb;
    return (unsigned short)(x >> 16);
}

// Radix-2 Stockham 512-pt FFT in LDS. One wave owns (x,y); 9 stages ping-pong.
// tw[k] = exp(-2*pi*i*k/512). inverse => conj twiddles (unnormalized).
// Returns pointer to buffer holding the result (== y for 9 stages).
__device__ inline float2* fft512_lds(float2* x, float2* y, const float2* tw,
                                     int lane, bool inverse)
{
    float2* src = x; float2* dst = y;
    int s = 1;
    #pragma unroll
    for (int n = NPT; n >= 2; n >>= 1) {
        const int m = n >> 1;
        const int tstep = NPT / n;
        #pragma unroll
        for (int k = 0; k < 4; ++k) {
            int t = lane + (k << 6);
            int p = t / s;
            int q = t - p * s;
            float2 a = src[q + s*p];
            float2 b = src[q + s*p + s*m];
            float2 w = tw[p * tstep];
            if (inverse) w.y = -w.y;
            float2 sum = make_float2(a.x + b.x, a.y + b.y);
            float2 dif = make_float2(a.x - b.x, a.y - b.y);
            float2 bw  = cmulf(dif, w);
            dst[q + 2*s*p]     = sum;
            dst[q + 2*s*p + s] = bw;
        }
        __syncthreads();
        float2* tmp = src; src = dst; dst = tmp;
        s <<= 1;
    }
    return src;
}

// prop = exp(i*kz*DZ); green = i*prop/(2kz)*mask; M = conj(prop^25)*prop^(2.0/0.1)*otf
__global__ __launch_bounds__(256)
void k_pre(const float* __restrict__ kz, const float* __restrict__ otfa,
           const float* __restrict__ gmask, const float* __restrict__ otfp,
           float2* __restrict__ prop, float2* __restrict__ green,
           float2* __restrict__ Mmul)
{
    int i = blockIdx.x * 256 + threadIdx.x;
    if (i >= HH * WW) return;
    float k = kz[i];
    float sn, cs;
    __sincosf(k * 0.1f, &sn, &cs);
    prop[i] = make_float2(cs, sn);
    float inv2 = 0.5f / k * gmask[i];
    green[i] = make_float2(-sn * inv2, cs * inv2);
    const float pf = (float)(2.0 / 0.1);   // 20.0f
    float phase = otfp[i] + k * 0.1f * (pf - 25.0f);
    float s2, c2;
    __sincosf(phase, &s2, &c2);
    float oa = otfa[i];
    Mmul[i] = make_float2(oa * c2, oa * s2);
}

// sample [B,H,W,S] f32 re/im -> sampT [S,B,H,W] bf16 complex (ushort2)
__global__ __launch_bounds__(256)
void k_transpose(const float* __restrict__ sre, const float* __restrict__ sim,
                 ushort2* __restrict__ sampT)
{
    __shared__ ushort2 tile[SS * 129];
    const int bh = blockIdx.x;            // b*H + h
    const int b = bh >> 9, h = bh & 511;
    const size_t src_base = (size_t)bh * (WW * SS);
    for (int chunk = 0; chunk < 4; ++chunk) {
        const int w0 = chunk * 128;
        __syncthreads();
        for (int j = threadIdx.x; j < 128 * SS; j += 256) {
            float re = sre[src_base + (size_t)w0 * SS + j];
            float im = sim[src_base + (size_t)w0 * SS + j];
            int w = j / SS;
            int s = j - w * SS;
            tile[s * 129 + w] = make_ushort2(f2bf(re), f2bf(im));
        }
        __syncthreads();
        for (int j = threadIdx.x; j < 128 * SS; j += 256) {
            int s = j >> 7, w = j & 127;
            sampT[(((size_t)s * BB + b) * HH + h) * WW + w0 + w] = tile[s * 129 + w];
        }
    }
}

// Row pass. 4 waves/block, one row each.
// mode 0: out = Fr(planewave)                   (init)
// mode 1: out = Fr( Br(in) * slab * DZ/512 )    (slice `slice`)
// mode 2: finout = |Br(in)/512| cropped         (final)
__global__ __launch_bounds__(256)
void k_row(const float2* in,
           const float* __restrict__ pw_re, const float* __restrict__ pw_im,
           const ushort2* __restrict__ sampT,
           const float* __restrict__ samp_re, const float* __restrict__ samp_im,
           float2* out, float* __restrict__ finout,
           int mode, int slice, int h0, int nrows)
{
    __shared__ float2 Xs[4][NPT];
    __shared__ float2 Ys[4][NPT];
    __shared__ float2 TW[NPT / 2];

    const int tid = threadIdx.x;
    const int lane = tid & 63;
    const int wv = tid >> 6;
    {
        float s, c;
        __sincosf(-6.28318530717958647692f * (float)tid / (float)NPT, &s, &c);
        TW[tid] = make_float2(c, s);
    }

    const int row = blockIdx.x * 4 + wv;
    const int b = row / nrows;
    const int h = h0 + (row - b * nrows);
    const size_t rbase = ((size_t)b * HH + h) * WW;

    if (mode == 0) {
        #pragma unroll
        for (int k = 0; k < 8; ++k) {
            int w = lane + (k << 6);
            Xs[wv][w] = make_float2(pw_re[rbase + w], pw_im[rbase + w]);
        }
        __syncthreads();
        float2* res = fft512_lds(Xs[wv], Ys[wv], TW, lane, false);
        #pragma unroll
        for (int k = 0; k < 8; ++k) {
            int w = lane + (k << 6);
            out[rbase + w] = res[w];
        }
        return;
    }

    #pragma unroll
    for (int k = 0; k < 8; ++k) {
        int w = lane + (k << 6);
        Xs[wv][w] = in[rbase + w];
    }
    __syncthreads();
    float2* res = fft512_lds(Xs[wv], Ys[wv], TW, lane, true);  // unnormalized Br

    if (mode == 2) {
        float* orow = finout + ((size_t)b * OUTW + (h - PADC)) * OUTW;
        #pragma unroll
        for (int k = 0; k < 8; ++k) {
            int w = lane + (k << 6);
            if (w >= PADC && w < WW - PADC) {
                float2 v = res[w];
                orow[w - PADC] = sqrtf(v.x * v.x + v.y * v.y) * (1.0f / (float)NPT);
            }
        }
        return;
    }

    // mode 1: multiply by slab * DZ/W, forward FFT
    const float scale = 0.1f / (float)NPT;
    #pragma unroll
    for (int k = 0; k < 8; ++k) {
        int w = lane + (k << 6);
        float sr, si;
        if (sampT) {
            ushort2 u = sampT[(((size_t)slice * BB + b) * HH + h) * WW + w];
            sr = bf2f(u.x); si = bf2f(u.y);
        } else {
            size_t idx = (rbase + w) * SS + slice;
            sr = samp_re[idx]; si = samp_im[idx];
        }
        float2 v = res[w];
        res[w] = make_float2((v.x * sr - v.y * si) * scale,
                             (v.x * si + v.y * sr) * scale);
    }
    __syncthreads();
    float2* other = (res == Ys[wv]) ? Xs[wv] : Ys[wv];
    float2* res2 = fft512_lds(res, other, TW, lane, false);
    #pragma unroll
    for (int k = 0; k < 8; ++k) {
        int w = lane + (k << 6);
        out[rbase + w] = res2[w];
    }
}

// Column pass. Block = 4 columns (one per wave), cooperative tile load.
// mode 0: inc = Fc(in)                                          (init)
// mode 1: s5=Fc(in); inc'=prop*inc+green*s5; inc=inc'; outA=(1/512)Bc(inc')
// mode 2: same but inc' *= M, no inc write; outA=(1/512)Bc(inc'*M)  (last slice)
__global__ __launch_bounds__(256)
void k_col(const float2* in,
           float2* __restrict__ incbuf,
           float2* outA,
           const float2* __restrict__ prop,
           const float2* __restrict__ green,
           const float2* __restrict__ Mmul,
           int mode)
{
    __shared__ float2 Xs[4][NPT];
    __shared__ float2 Ys[4][NPT];
    __shared__ float2 TW[NPT / 2];

    const int tid = threadIdx.x;
    const int lane = tid & 63;
    const int wv = tid >> 6;
    {
        float s, c;
        __sincosf(-6.28318530717958647692f * (float)tid / (float)NPT, &s, &c);
        TW[tid] = make_float2(c, s);
    }

    const int b = blockIdx.x >> 7;
    const int w0 = (blockIdx.x & 127) << 2;
    const size_t base = (size_t)b * HH * WW + w0;

    #pragma unroll
    for (int k = 0; k < 8; ++k) {
        int j = tid + (k << 8);
        int h = j >> 2, c = j & 3;
        Xs[c][h] = in[base + (size_t)h * WW + c];
    }
    __syncthreads();
    fft512_lds(Xs[wv], Ys[wv], TW, lane, false);   // result in Ys

    if (mode == 0) {
        #pragma unroll
        for (int k = 0; k < 8; ++k) {
            int j = tid + (k << 8);
            int h = j >> 2, c = j & 3;
            incbuf[base + (size_t)h * WW + c] = Ys[c][h];
        }
        return;
    }

    #pragma unroll
    for (int k = 0; k < 8; ++k) {
        int j = tid + (k << 8);
        int h = j >> 2, c = j & 3;
        size_t gidx = base + (size_t)h * WW + c;
        size_t pidx = (size_t)h * WW + w0 + c;
        float2 s5 = Ys[c][h];
        float2 p = prop[pidx];
        float2 g = green[pidx];
        float2 io = incbuf[gidx];
        float2 nw = make_float2(p.x*io.x - p.y*io.y + g.x*s5.x - g.y*s5.y,
                                p.x*io.y + p.y*io.x + g.x*s5.y + g.y*s5.x);
        if (mode == 2) {
            nw = cmulf(nw, Mmul[pidx]);
        } else {
            incbuf[gidx] = nw;
        }
        Xs[c][h] = nw;
    }
    __syncthreads();
    fft512_lds(Xs[wv], Ys[wv], TW, lane, true);    // result in Ys
    const float inv = 1.0f / (float)NPT;
    #pragma unroll
    for (int k = 0; k < 8; ++k) {
        int j = tid + (k << 8);
        int h = j >> 2, c = j & 3;
        float2 v = Ys[c][h];
        outA[base + (size_t)h * WW + c] = make_float2(v.x * inv, v.y * inv);
    }
}

extern "C" void kernel_launch(void* const* d_in, const int* in_sizes, int n_in,
                              void* d_out, int out_size, void* d_ws, size_t ws_size,
                              hipStream_t stream)
{
    (void)in_sizes; (void)n_in; (void)out_size;
    const float* sre   = (const float*)d_in[0];
    const float* simg  = (const float*)d_in[1];
    const float* pwre  = (const float*)d_in[2];
    const float* pwim  = (const float*)d_in[3];
    const float* kz    = (const float*)d_in[4];
    const float* otfa  = (const float*)d_in[5];
    const float* gmask = (const float*)d_in[6];
    const float* otfp  = (const float*)d_in[7];

    char* ws = (char*)d_ws;
    size_t off = 0;
    float2* prop  = (float2*)(ws + off); off += (size_t)HH * WW * 8;
    float2* green = (float2*)(ws + off); off += (size_t)HH * WW * 8;
    float2* Mmul  = (float2*)(ws + off); off += (size_t)HH * WW * 8;
    float2* inc   = (float2*)(ws + off); off += (size_t)BB * HH * WW * 8;
    float2* fld   = (float2*)(ws + off); off += (size_t)BB * HH * WW * 8;
    ushort2* sampT = (ushort2*)(ws + off);
    const size_t need = off + (size_t)SS * BB * HH * WW * 4;
    const bool useT = (ws_size >= need);
    if (!useT) sampT = nullptr;

    k_pre<<<(HH * WW + 255) / 256, 256, 0, stream>>>(kz, otfa, gmask, otfp,
                                                     prop, green, Mmul);
    if (useT)
        k_transpose<<<BB * HH, 256, 0, stream>>>(sre, simg, sampT);

    // fld = Fr(planewave)
    k_row<<<512, 256, 0, stream>>>(nullptr, pwre, pwim, nullptr, nullptr, nullptr,
                                   fld, nullptr, 0, 0, 0, 512);
    // inc = Fc(fld)
    k_col<<<512, 256, 0, stream>>>(fld, inc, nullptr, prop, green, Mmul, 0);

    for (int s = 0; s < SS; ++s) {
        k_row<<<512, 256, 0, stream>>>(fld, nullptr, nullptr, sampT, sre, simg,
                                       fld, nullptr, 1, s, 0, 512);
        k_col<<<512, 256, 0, stream>>>(fld, inc, fld, prop, green, Mmul,
                                       (s == SS - 1) ? 2 : 1);
    }
    // final: |Br(fld)/512| cropped rows h in [32,480)
    k_row<<<448, 256, 0, stream>>>(fld, nullptr, nullptr, nullptr, nullptr, nullptr,
                                   nullptr, (float*)d_out, 2, 0, PADC, 448);
}

// Round 2
// 1354.867 us; speedup vs baseline: 1.4385x; 1.4385x over previous
//
#include <hip/hip_runtime.h>
#include <math.h>

#define HW_ (512 * 512)

__device__ inline float2 cadd(float2 a, float2 b){ return make_float2(a.x+b.x, a.y+b.y); }
__device__ inline float2 csub(float2 a, float2 b){ return make_float2(a.x-b.x, a.y-b.y); }
__device__ inline float2 cmulf(float2 a, float2 b){ return make_float2(a.x*b.x-a.y*b.y, a.x*b.y+a.y*b.x); }
__device__ inline float bf2f(unsigned short u){ return __uint_as_float(((unsigned int)u) << 16); }
__device__ inline unsigned short f2bf(float f){
    unsigned int x = __float_as_uint(f);
    x += 0x7fffu + ((x >> 16) & 1u);
    return (unsigned short)(x >> 16);
}

// ---------- 8-point DFT in registers, natural-order output ----------
template<bool INV>
__device__ inline void dft8(const float2 a[8], float2 X[8]) {
    const float C = 0.70710678118654752440f;
    float2 t0 = cadd(a[0], a[4]), t4 = csub(a[0], a[4]);
    float2 t1 = cadd(a[1], a[5]), d1 = csub(a[1], a[5]);
    float2 t2 = cadd(a[2], a[6]), d2 = csub(a[2], a[6]);
    float2 t3 = cadd(a[3], a[7]), d3 = csub(a[3], a[7]);
    float2 t5, t6, t7;
    if (!INV) {
        t5 = make_float2(C*(d1.x + d1.y), C*(d1.y - d1.x));   // * (C,-C)
        t6 = make_float2(d2.y, -d2.x);                        // * -i
        t7 = make_float2(C*(d3.y - d3.x), -C*(d3.x + d3.y));  // * (-C,-C)
    } else {
        t5 = make_float2(C*(d1.x - d1.y), C*(d1.y + d1.x));   // * (C,C)
        t6 = make_float2(-d2.y, d2.x);                        // * +i
        t7 = make_float2(-C*(d3.x + d3.y), C*(d3.x - d3.y));  // * (-C,C)
    }
    float2 u0 = cadd(t0, t2), u2 = csub(t0, t2);
    float2 u1 = cadd(t1, t3), e3 = csub(t1, t3);
    float2 u3 = INV ? make_float2(-e3.y, e3.x) : make_float2(e3.y, -e3.x);
    float2 u4 = cadd(t4, t6), u6 = csub(t4, t6);
    float2 u5 = cadd(t5, t7), e7 = csub(t5, t7);
    float2 u7 = INV ? make_float2(-e7.y, e7.x) : make_float2(e7.y, -e7.x);
    X[0] = cadd(u0, u1); X[4] = csub(u0, u1);
    X[2] = cadd(u2, u3); X[6] = csub(u2, u3);
    X[1] = cadd(u4, u5); X[5] = csub(u4, u5);
    X[3] = cadd(u6, u7); X[7] = csub(u6, u7);
}

// ---------- 512-pt FFT: radix-8^3 Stockham, registers + 2 LDS exchanges ----------
// Entry: a[j] = x[lane + 64*j].  Exit: a[k] = X[lane + 64*k] (natural order).
// xch: 576-float2 wave-private LDS region. T1/T2 are FORWARD twiddle bases
// exp(-2pi i lane/512), exp(-2pi i (lane>>3)/64); conjugated internally if INV.
template<bool INV>
__device__ inline void fft512_reg(float2 a[8], float2* __restrict__ xch,
                                  int lane, float2 T1, float2 T2)
{
    float2 tw1 = INV ? make_float2(T1.x, -T1.y) : T1;
    float2 tw2 = INV ? make_float2(T2.x, -T2.y) : T2;
    const int rdo = lane + (lane >> 3);        // read offset base (skewed)
    float2 b[8];

    // stage 1: n=512, s=1, p=lane
    dft8<INV>(a, b);
    { float2 w = tw1;
      #pragma unroll
      for (int k = 1; k < 8; ++k) { b[k] = cmulf(b[k], w); w = cmulf(w, tw1); } }
    #pragma unroll
    for (int k = 0; k < 8; ++k) xch[9*lane + k] = b[k];   // e=8t+k -> e+(e>>3)
    __asm__ volatile("s_waitcnt lgkmcnt(0)" ::: "memory");
    #pragma unroll
    for (int j = 0; j < 8; ++j) a[j] = xch[rdo + 72*j];   // e=t+64j

    // stage 2: n=64, s=8, p=lane>>3, q=lane&7
    dft8<INV>(a, b);
    { float2 w = tw2;
      #pragma unroll
      for (int k = 1; k < 8; ++k) { b[k] = cmulf(b[k], w); w = cmulf(w, tw2); } }
    { const int wbase = (lane & 7) + 72 * (lane >> 3);    // e=q+64p+8k -> q+72p+9k
      #pragma unroll
      for (int k = 0; k < 8; ++k) xch[wbase + 9*k] = b[k]; }
    __asm__ volatile("s_waitcnt lgkmcnt(0)" ::: "memory");
    #pragma unroll
    for (int j = 0; j < 8; ++j) b[j] = xch[rdo + 72*j];

    // stage 3: n=8, s=64, p=0 (no twiddle), output natural order
    dft8<INV>(b, a);
}

// ---------- constants: propT/greenT/MT in TRANSPOSED [w][h] layout ----------
__global__ __launch_bounds__(256)
void k_pre(const float* __restrict__ kz, const float* __restrict__ otfa,
           const float* __restrict__ gmask, const float* __restrict__ otfp,
           float2* __restrict__ propT, float2* __restrict__ greenT,
           float2* __restrict__ MT)
{
    __shared__ float2 tp[32*33], tg[32*33], tm[32*33];
    const int tid = threadIdx.x;
    const int w0 = (blockIdx.x & 15) << 5;
    const int h0 = (blockIdx.x >> 4) << 5;
    const int ww = tid & 31, hh = tid >> 5;   // hh 0..7
    #pragma unroll
    for (int p = 0; p < 4; ++p) {
        int h = hh + p*8;
        int idx = (h0 + h)*512 + w0 + ww;
        float k = kz[idx];
        float sn, cs; __sincosf(k * 0.1f, &sn, &cs);
        float inv2 = 0.5f / k * gmask[idx];
        float phase = otfp[idx] - k * 0.5f;     // otfp + kz*DZ*(20-25)
        float s2, c2; __sincosf(phase, &s2, &c2);
        float oa = otfa[idx];
        tp[h*33 + ww] = make_float2(cs, sn);
        tg[h*33 + ww] = make_float2(-sn*inv2, cs*inv2);
        tm[h*33 + ww] = make_float2(oa*c2, oa*s2);
    }
    __syncthreads();
    #pragma unroll
    for (int p = 0; p < 4; ++p) {
        int wrow = hh + p*8;
        size_t o = (size_t)(w0 + wrow)*512 + h0 + ww;
        propT[o]  = tp[ww*33 + wrow];
        greenT[o] = tg[ww*33 + wrow];
        MT[o]     = tm[ww*33 + wrow];
    }
}

// ---------- sample [B,H,W,S] f32 -> sampT [S,B,H,W] bf16 complex ----------
__global__ __launch_bounds__(256)
void k_transpose(const float* __restrict__ sre, const float* __restrict__ sim,
                 ushort2* __restrict__ sampT)
{
    __shared__ ushort2 tile[40 * 129];
    const int bh = blockIdx.x;               // b*512 + h
    const int b = bh >> 9, h = bh & 511;
    const size_t src_base = (size_t)bh * (512 * 40);
    const float2* sre2 = (const float2*)(sre + src_base);
    const float2* sim2 = (const float2*)(sim + src_base);
    for (int chunk = 0; chunk < 4; ++chunk) {
        const int w0 = chunk * 128;
        const int base2 = w0 * 20;           // float2 index (w0*40/2)
        __syncthreads();
        for (int j = threadIdx.x; j < 128 * 20; j += 256) {
            float2 re = sre2[base2 + j];
            float2 im = sim2[base2 + j];
            int w = j / 20;
            int s = (j - w * 20) * 2;
            tile[s*129 + w]       = make_ushort2(f2bf(re.x), f2bf(im.x));
            tile[(s+1)*129 + w]   = make_ushort2(f2bf(re.y), f2bf(im.y));
        }
        __syncthreads();
        for (int j = threadIdx.x; j < 40 * 64; j += 256) {
            int s = j >> 6, w2 = (j & 63) << 1;
            ushort2 u0 = tile[s*129 + w2], u1 = tile[s*129 + w2 + 1];
            *(ushort4*)&sampT[(((size_t)s*4 + b)*512 + h)*512 + w0 + w2] =
                make_ushort4(u0.x, u0.y, u1.x, u1.y);
        }
    }
}

// ---------- row pass (natural layout): wave per row ----------
// mode 0: fld = Fr(planewave)
// mode 1: fld = Fr( Br(fld) * slab * DZ/512 )
// mode 2: out = |Br(fld)|/512, cropped
__global__ __launch_bounds__(256)
void k_row(float2* __restrict__ fld,
           const float* __restrict__ pwre, const float* __restrict__ pwim,
           const ushort2* __restrict__ sampT,
           float* __restrict__ finout,
           int mode, int slice)
{
    __shared__ float2 xchall[4 * 576];
    const int tid = threadIdx.x, lane = tid & 63, wv = tid >> 6;
    float2* xch = &xchall[wv * 576];
    float s1, c1, s2, c2;
    __sincosf(-6.2831853071795864769f * (float)lane / 512.0f, &s1, &c1);
    __sincosf(-6.2831853071795864769f * (float)(lane >> 3) / 64.0f, &s2, &c2);
    const float2 T1 = make_float2(c1, s1), T2 = make_float2(c2, s2);

    const int r = blockIdx.x * 4 + wv;
    int b, h;
    if (mode == 2) { b = r / 448; h = 32 + (r - b * 448); }
    else           { b = r >> 9;  h = r & 511; }
    const size_t rbase = ((size_t)b * 512 + h) * 512;
    float2 a[8];

    if (mode == 0) {
        #pragma unroll
        for (int j = 0; j < 8; ++j) {
            int w = lane + (j << 6);
            a[j] = make_float2(pwre[rbase + w], pwim[rbase + w]);
        }
        fft512_reg<false>(a, xch, lane, T1, T2);
        #pragma unroll
        for (int j = 0; j < 8; ++j) fld[rbase + lane + (j << 6)] = a[j];
        return;
    }

    #pragma unroll
    for (int j = 0; j < 8; ++j) a[j] = fld[rbase + lane + (j << 6)];
    fft512_reg<true>(a, xch, lane, T1, T2);    // unnormalized Br

    if (mode == 2) {
        float* orow = finout + ((size_t)b * 448 + (h - 32)) * 448;
        #pragma unroll
        for (int j = 0; j < 8; ++j) {
            int w = lane + (j << 6);
            if (w >= 32 && w < 480) {
                float2 v = a[j];
                orow[w - 32] = sqrtf(v.x*v.x + v.y*v.y) * (1.0f / 512.0f);
            }
        }
        return;
    }

    const float scale = 0.1f / 512.0f;         // DZ * (1/512 column-inverse norm)
    const size_t sbase = (((size_t)slice * 4 + b) * 512 + h) * 512;
    #pragma unroll
    for (int j = 0; j < 8; ++j) {
        int w = lane + (j << 6);
        ushort2 u = sampT[sbase + w];
        float sr = bf2f(u.x), si = bf2f(u.y);
        float2 v = a[j];
        a[j] = make_float2((v.x*sr - v.y*si) * scale, (v.x*si + v.y*sr) * scale);
    }
    fft512_reg<false>(a, xch, lane, T1, T2);
    #pragma unroll
    for (int j = 0; j < 8; ++j) fld[rbase + lane + (j << 6)] = a[j];
}

// ---------- column pass: 8 columns/block, wave per column ----------
// Fourier arrays transposed [b][w][h]; fld natural [b][h][w] via LDS tile.
// mode 0: incT = Fc(fld)
// mode 1: s5=Fc(fld); nw=prop*inc+green*s5; incT=nw; fld=(1/512)Bc(nw)
// mode 2: same but nw*=M, no incT write (last slice)
__global__ __launch_bounds__(512)
void k_col(float2* __restrict__ fld,
           float2* __restrict__ incT,
           const float2* __restrict__ propT, const float2* __restrict__ greenT,
           const float2* __restrict__ MT, int mode)
{
    __shared__ float2 tile[512 * 9];           // also the 8 wave-private xch regions
    const int tid = threadIdx.x;
    const int lane = tid & 63, wv = tid >> 6;  // wv 0..7
    const int b = blockIdx.x >> 6;
    const int w0 = (blockIdx.x & 63) << 3;
    const int c = tid & 7, hb = tid >> 3;      // cooperative load mapping
    const size_t gbase = (size_t)b * HW_ + w0;

    float s1, c1, s2, c2;
    __sincosf(-6.2831853071795864769f * (float)lane / 512.0f, &s1, &c1);
    __sincosf(-6.2831853071795864769f * (float)(lane >> 3) / 64.0f, &s2, &c2);
    const float2 T1 = make_float2(c1, s1), T2 = make_float2(c2, s2);

    #pragma unroll
    for (int j = 0; j < 8; ++j) {
        int h = hb + (j << 6);
        tile[h*9 + c] = fld[gbase + (size_t)h * 512 + c];
    }
    __syncthreads();
    float2 a[8];
    const int w = w0 + wv;
    #pragma unroll
    for (int j = 0; j < 8; ++j) a[j] = tile[(lane + (j << 6)) * 9 + wv];
    __syncthreads();                            // tile dead; becomes xch regions
    float2* xch = &tile[wv * 576];

    fft512_reg<false>(a, xch, lane, T1, T2);    // s5 (or Fc for init)

    const size_t ibase = ((size_t)b * 512 + w) * 512;
    const size_t pbase = (size_t)w * 512;
    if (mode == 0) {
        #pragma unroll
        for (int k = 0; k < 8; ++k) incT[ibase + lane + (k << 6)] = a[k];
        return;
    }
    #pragma unroll
    for (int k = 0; k < 8; ++k) {
        int h = lane + (k << 6);
        float2 p  = propT[pbase + h];
        float2 g  = greenT[pbase + h];
        float2 io = incT[ibase + h];
        float2 nw = make_float2(p.x*io.x - p.y*io.y + g.x*a[k].x - g.y*a[k].y,
                                p.x*io.y + p.y*io.x + g.x*a[k].y + g.y*a[k].x);
        if (mode == 2) nw = cmulf(nw, MT[pbase + h]);
        else           incT[ibase + h] = nw;
        a[k] = nw;
    }

    fft512_reg<true>(a, xch, lane, T1, T2);     // Bc, unnormalized
    __syncthreads();                            // all waves done with xch
    const float inv = 1.0f / 512.0f;
    #pragma unroll
    for (int k = 0; k < 8; ++k)
        tile[(lane + (k << 6)) * 9 + wv] = make_float2(a[k].x * inv, a[k].y * inv);
    __syncthreads();
    #pragma unroll
    for (int j = 0; j < 8; ++j) {
        int h = hb + (j << 6);
        fld[gbase + (size_t)h * 512 + c] = tile[h*9 + c];
    }
}

extern "C" void kernel_launch(void* const* d_in, const int* in_sizes, int n_in,
                              void* d_out, int out_size, void* d_ws, size_t ws_size,
                              hipStream_t stream)
{
    (void)in_sizes; (void)n_in; (void)out_size; (void)ws_size;
    const float* sre   = (const float*)d_in[0];
    const float* simg  = (const float*)d_in[1];
    const float* pwre  = (const float*)d_in[2];
    const float* pwim  = (const float*)d_in[3];
    const float* kz    = (const float*)d_in[4];
    const float* otfa  = (const float*)d_in[5];
    const float* gmask = (const float*)d_in[6];
    const float* otfp  = (const float*)d_in[7];

    char* ws = (char*)d_ws;
    size_t off = 0;
    float2* propT  = (float2*)(ws + off); off += (size_t)HW_ * 8;
    float2* greenT = (float2*)(ws + off); off += (size_t)HW_ * 8;
    float2* MT     = (float2*)(ws + off); off += (size_t)HW_ * 8;
    float2* incT   = (float2*)(ws + off); off += (size_t)4 * HW_ * 8;
    float2* fld    = (float2*)(ws + off); off += (size_t)4 * HW_ * 8;
    ushort2* sampT = (ushort2*)(ws + off);

    k_pre<<<256, 256, 0, stream>>>(kz, otfa, gmask, otfp, propT, greenT, MT);
    k_transpose<<<2048, 256, 0, stream>>>(sre, simg, sampT);

    // fld = Fr(planewave); incT = Fc(fld) = fft2(pw).  Note Bc(incT)/512 == fld.
    k_row<<<512, 256, 0, stream>>>(fld, pwre, pwim, nullptr, nullptr, 0, 0);
    k_col<<<256, 512, 0, stream>>>(fld, incT, propT, greenT, MT, 0);

    for (int s = 0; s < 40; ++s) {
        k_row<<<512, 256, 0, stream>>>(fld, nullptr, nullptr, sampT, nullptr, 1, s);
        k_col<<<256, 512, 0, stream>>>(fld, incT, propT, greenT, MT, (s == 39) ? 2 : 1);
    }
    // out = |Br(fld)|/512, rows 32..479, cols 32..479
    k_row<<<448, 256, 0, stream>>>(fld, nullptr, nullptr, nullptr, (float*)d_out, 2, 0);
}